// Round 6
// baseline (175.326 us; speedup 1.0000x reference)
//
#include <hip/hip_runtime.h>

#define BB 16384
#define DD 256
#define EE 8
#define HH 128
#define TBLK 96           // transpose blocks
#define XS_S 264          // 256 + 8 bf16 pad (16B-aligned rows)
#define CS_S 136          // 128 + 8 bf16 pad

typedef __attribute__((ext_vector_type(8))) short short8;   // 8 bf16 = 4 VGPRs
typedef __attribute__((ext_vector_type(4))) float f32x4;

// fp32 -> bf16 round-to-nearest-even (values are finite; no NaN care needed)
__device__ __forceinline__ ushort f2bf(float f){
    const unsigned u = __float_as_uint(f);
    return (ushort)((u + 0x7fffu + ((u >> 16) & 1u)) >> 16);
}
__device__ __forceinline__ float bf2f(ushort s){
    return __uint_as_float(((unsigned)s) << 16);
}
__device__ __forceinline__ float fast_tanh(float v){
    v = fminf(fmaxf(v, -15.0f), 15.0f);
    const float a = __expf(2.0f * v);
    return (a - 1.0f) / (a + 1.0f);
}

// ---------------------------------------------------------------------------
// Prep (transpose-only): W1 [e][k=256][h=128] fp32 -> W1t [e][h][k] bf16;
// Wp likewise. 96 blocks of 64x64 tiles. ~1.5 MB read -> tiny kernel.
__global__ __launch_bounds__(256) void prep_kernel(
    const float* __restrict__ W1, const float* __restrict__ Wp,
    ushort* __restrict__ W1t, ushort* __restrict__ Wpt)
{
    __shared__ float tile[64 * 68];   // 64x64 fp32 tile, pad 68 vs bank conflicts
    int b = blockIdx.x;
    const int t = threadIdx.x;
    const float* src; ushort* dst; int K;
    int k0, h0;
    if (b < 64){                                    // W1: 8e x 4kt x 2ht
        const int e = b >> 3, kt = (b >> 1) & 3, ht = b & 1;
        src = W1 + (size_t)e * DD * HH;  dst = W1t + (size_t)e * HH * DD;
        K = DD; k0 = kt * 64; h0 = ht * 64;
    } else {                                        // Wp: 8e x 2kt x 2ht
        b -= 64;
        const int e = b >> 2, kt = (b >> 1) & 1, ht = b & 1;
        src = Wp + (size_t)e * HH * HH;  dst = Wpt + (size_t)e * HH * HH;
        K = HH; k0 = kt * 64; h0 = ht * 64;
    }
    #pragma unroll
    for (int j = 0; j < 4; j++){
        const int idx = t + 256 * j;               // 1024 float4 = 64x64
        const int kk = idx >> 4, hh = (idx & 15) * 4;
        const float4 v = *(const float4*)(src + (size_t)(k0 + kk) * HH + h0 + hh);
        *(float4*)&tile[kk * 68 + hh] = v;
    }
    __syncthreads();
    #pragma unroll
    for (int j = 0; j < 4; j++){
        const int idx = t + 256 * j;
        const int hh = idx >> 4, kk = (idx & 15) * 4;
        ushort4 o;
        o.x = f2bf(tile[(kk + 0) * 68 + hh]);
        o.y = f2bf(tile[(kk + 1) * 68 + hh]);
        o.z = f2bf(tile[(kk + 2) * 68 + hh]);
        o.w = f2bf(tile[(kk + 3) * 68 + hh]);
        *(ushort4*)&dst[(size_t)(h0 + hh) * K + k0 + kk] = o;
    }
}

// ---------------------------------------------------------------------------
// Dense kernel v2 (bugfixed): 512 blocks x 512 threads, 32 rows/block,
// ~35 KB LDS -> 2 blocks/CU, 4 waves/SIMD.
//
// Self-contained: stages X (fp32->bf16), routes its own 32 rows with
// BIT-IDENTICAL gating math, then computes all 8 experts densely; per-row
// top-2 weights select contributions (w=0 exactly for non-picked experts).
//
// Wave layout: 8 waves = 2 row-halves x 4 col-quarters.
//   wave w: rows r0=16*(w>>2) (+m16), cols c0=32*(w&3) (2 x 16-col tiles).
// Per expert e (8 sub-iterations, one shared coreS[32][136]):
//   wES <- per-row weight; GEMM1 (K=256) -> relu -> coreS;  barrier;
//   GEMM2 (K=128) -> tanh-mix epilogue partial -> red;      barrier.
// Final: shfl-reduce over m16, redS[4][32] cross-quarter sum, single store.
//
// ROUND-5 BUG FIXED HERE: epilogue weight index was
// wES[row - rowBase - r0 + r0] (= row - rowBase, hugely negative for
// blockIdx.x > 0 since row is block-local). Correct index is wES[row].
__global__ __launch_bounds__(512, 4) void dense_kernel(
    const float* __restrict__ x, const float* __restrict__ Wg,
    const ushort* __restrict__ W1t, const float* __restrict__ b1,
    const ushort* __restrict__ Wpt, const float* __restrict__ bp,
    const float* __restrict__ mix_logit, const float* __restrict__ Wo,
    const float* __restrict__ bo, float* __restrict__ out)
{
    __shared__ __align__(16) float WgT[EE][DD];   // 8 KB
    __shared__ ushort Xs[32 * XS_S];              // 16.5 KB
    __shared__ ushort coreS[32 * CS_S];           // 8.5 KB
    __shared__ int    le[64];                     // slot s: e0 at [s], e1 at [32+s]
    __shared__ float  lw[64];
    __shared__ float  wES[32];
    __shared__ float  redS[4][32];
    __shared__ float  mvS[EE], boS[EE];

    const int t = threadIdx.x;
    const int rowBase = blockIdx.x * 32;
    const int lane = t & 63;
    const int wid  = t >> 6;

    // ---- stage WgT (t<256, same pattern as verified routing) + consts ----
    if (t < 256){
        const float4* g = (const float4*)(Wg + t * EE);
        const float4 a = g[0], b = g[1];
        WgT[0][t] = a.x; WgT[1][t] = a.y; WgT[2][t] = a.z; WgT[3][t] = a.w;
        WgT[4][t] = b.x; WgT[5][t] = b.y; WgT[6][t] = b.z; WgT[7][t] = b.w;
    }
    if (t < EE){ mvS[t] = 1.0f / (1.0f + __expf(-mix_logit[t])); boS[t] = bo[t]; }

    // ---- stage Xs: 32 rows x 256 cols bf16, 2 chunks (8 bf16) per thread ----
    #pragma unroll
    for (int i = 0; i < 2; i++){
        const int c   = t * 2 + i;                 // 1024 chunks
        const int row = c >> 5, cc = c & 31;
        const float* xp = x + (size_t)(rowBase + row) * DD + cc * 8;
        const float4 v0 = *(const float4*)xp;
        const float4 v1 = *(const float4*)(xp + 4);
        short8 o;
        o[0] = (short)f2bf(v0.x); o[1] = (short)f2bf(v0.y);
        o[2] = (short)f2bf(v0.z); o[3] = (short)f2bf(v0.w);
        o[4] = (short)f2bf(v1.x); o[5] = (short)f2bf(v1.y);
        o[6] = (short)f2bf(v1.z); o[7] = (short)f2bf(v1.w);
        *(short8*)&Xs[row * XS_S + cc * 8] = o;
    }
    __syncthreads();

    // ---- routing: 8 waves x 4 rows, per-row math bit-identical to verified ----
    for (int it = 0; it < 4; it++){
        const int slot = wid * 4 + it;
        const int row  = rowBase + slot;
        const float4 xv = *(const float4*)(x + (size_t)row * DD + lane * 4);
        float p[EE];
        #pragma unroll
        for (int e = 0; e < EE; e++){
            const float4 ww = *(const float4*)&WgT[e][lane * 4];
            p[e] = xv.x * ww.x + xv.y * ww.y + xv.z * ww.z + xv.w * ww.w;
        }
        #pragma unroll
        for (int off = 32; off >= 1; off >>= 1){
            #pragma unroll
            for (int e = 0; e < EE; e++) p[e] += __shfl_down(p[e], off, 64);
        }
        if (lane == 0){
            int e0 = 0; float l0 = p[0];
            #pragma unroll
            for (int e = 1; e < EE; e++){ if (p[e] > l0){ l0 = p[e]; e0 = e; } }
            int e1 = -1; float l1 = -3.0e38f;
            #pragma unroll
            for (int e = 0; e < EE; e++){ if (e != e0 && p[e] > l1){ l1 = p[e]; e1 = e; } }
            const float tt  = __expf(l1 - l0);            // <= 1
            const float inv = 1.0f / (1.0f + tt);
            le[slot]      = e0;  lw[slot]      = inv;
            le[32 + slot] = e1;  lw[32 + slot] = tt * inv;
        }
    }
    __syncthreads();

    // ---- dense expert loop ----
    const int m16   = lane & 15;
    const int q     = lane >> 4;
    const int rhalf = wid >> 2;
    const int cq    = wid & 3;
    const int r0    = rhalf * 16;
    const int c0    = cq * 32;

    float red[4] = {0.0f, 0.0f, 0.0f, 0.0f};      // rows r0 + q*4 + j

    #pragma unroll 1
    for (int e = 0; e < EE; e++){
        // per-row weight for this expert (0 if not in the row's top-2)
        if (t < 32)
            wES[t] = (le[t] == e) ? lw[t] : ((le[32 + t] == e) ? lw[32 + t] : 0.0f);

        // ---- GEMM1: core_pre = X @ W1[e] + b1[e]  (16 rows x 32 cols/wave) ----
        f32x4 acc[2];
        #pragma unroll
        for (int ct = 0; ct < 2; ct++){
            const float bj = b1[e * HH + c0 + ct * 16 + m16];
            acc[ct] = (f32x4){bj, bj, bj, bj};
        }
        const ushort* W1te = W1t + (size_t)e * HH * DD;
        #pragma unroll
        for (int ks = 0; ks < 8; ks++){
            const short8 af = *(const short8*)&Xs[(r0 + m16) * XS_S + ks * 32 + q * 8];
            #pragma unroll
            for (int ct = 0; ct < 2; ct++){
                const short8 bfr = *(const short8*)&W1te[(size_t)(c0 + ct * 16 + m16) * DD + ks * 32 + q * 8];
                acc[ct] = __builtin_amdgcn_mfma_f32_16x16x32_bf16(af, bfr, acc[ct], 0, 0, 0);
            }
        }
        // relu -> bf16 core into shared coreS
        #pragma unroll
        for (int ct = 0; ct < 2; ct++)
            #pragma unroll
            for (int j = 0; j < 4; j++)
                coreS[(r0 + q * 4 + j) * CS_S + c0 + ct * 16 + m16] =
                    f2bf(fmaxf(acc[ct][j], 0.0f));
        __syncthreads();   // coreS + wES visible to all waves

        // ---- GEMM2: plast_pre = core @ Wp[e] + bp[e] ----
        f32x4 acc2[2];
        #pragma unroll
        for (int ct = 0; ct < 2; ct++){
            const float bj = bp[e * HH + c0 + ct * 16 + m16];
            acc2[ct] = (f32x4){bj, bj, bj, bj};
        }
        const ushort* Wpte = Wpt + (size_t)e * HH * HH;
        #pragma unroll
        for (int ks = 0; ks < 4; ks++){
            const short8 af2 = *(const short8*)&coreS[(r0 + m16) * CS_S + ks * 32 + q * 8];
            #pragma unroll
            for (int ct = 0; ct < 2; ct++){
                const short8 bfr = *(const short8*)&Wpte[(size_t)(c0 + ct * 16 + m16) * HH + ks * 32 + q * 8];
                acc2[ct] = __builtin_amdgcn_mfma_f32_16x16x32_bf16(af2, bfr, acc2[ct], 0, 0, 0);
            }
        }

        // ---- epilogue partial: red += w_row * (sum_cols + bo[e] on quarter 0) ----
        const float mv   = mvS[e];
        const float om   = 1.0f - mv;
        const float badd = (cq == 0) ? boS[e] : 0.0f;
        float wo[2];
        #pragma unroll
        for (int ct = 0; ct < 2; ct++) wo[ct] = Wo[e * HH + c0 + ct * 16 + m16];

        #pragma unroll
        for (int j = 0; j < 4; j++){
            const int row = r0 + q * 4 + j;        // block-local row (0..31)
            float s = 0.0f;
            #pragma unroll
            for (int ct = 0; ct < 2; ct++){
                const int col = c0 + ct * 16 + m16;
                const float pl = fast_tanh(acc2[ct][j]);
                const float cv = bf2f(coreS[row * CS_S + col]);
                s = fmaf(om * cv + mv * pl, wo[ct], s);
            }
            red[j] = fmaf(wES[row], s + badd, red[j]);   // FIXED: was wES[row - rowBase]
        }
        __syncthreads();   // coreS/wES consumed; next e may overwrite
    }

    // ---- final: reduce over m16, cross-quarter sum via redS, single store ----
    #pragma unroll
    for (int off = 8; off >= 1; off >>= 1)
        #pragma unroll
        for (int j = 0; j < 4; j++)
            red[j] += __shfl_xor(red[j], off, 64);

    if (m16 == 0)
        #pragma unroll
        for (int j = 0; j < 4; j++)
            redS[cq][r0 + q * 4 + j] = red[j];
    __syncthreads();

    if (t < 32)
        out[rowBase + t] = redS[0][t] + redS[1][t] + redS[2][t] + redS[3][t];
}

// ---------------------------------------------------------------------------
extern "C" void kernel_launch(void* const* d_in, const int* in_sizes, int n_in,
                              void* d_out, int out_size, void* d_ws, size_t ws_size,
                              hipStream_t stream) {
    (void)in_sizes; (void)n_in; (void)out_size; (void)ws_size;
    const float* x   = (const float*)d_in[0];
    const float* Wg  = (const float*)d_in[1];
    const float* W1  = (const float*)d_in[2];
    const float* b1  = (const float*)d_in[3];
    const float* Wp  = (const float*)d_in[4];
    const float* bp  = (const float*)d_in[5];
    const float* ml  = (const float*)d_in[6];
    const float* Wo  = (const float*)d_in[7];
    const float* bo  = (const float*)d_in[8];
    float* out = (float*)d_out;

    // ws layout: W1t E*H*D*2 = 512 KB | Wpt E*H*H*2 = 256 KB. Nothing else.
    char*   ws  = (char*)d_ws;
    ushort* W1t = (ushort*)ws;
    ushort* Wpt = W1t + (size_t)EE * HH * DD;

    // 2 dispatches, no memsets, no atomics, no gather.
    prep_kernel<<<TBLK, 256, 0, stream>>>(W1, Wp, W1t, Wpt);
    dense_kernel<<<BB / 32, 512, 0, stream>>>(
        x, Wg, W1t, b1, Wpt, bp, ml, Wo, bo, out);
}

// Round 7
// 129.397 us; speedup vs baseline: 1.3549x; 1.3549x over previous
//
#include <hip/hip_runtime.h>

#define BB 16384
#define DD 256
#define EE 8
#define HH 128
#define TBLK 96           // transpose blocks
#define RPB 64            // rows per dense block
#define XS_S 264          // 256 + 8 bf16 pad (rotates 16B chunk->bank slot by 1/row)
#define CS_S 136          // 128 + 8 bf16 pad (same rotation)

typedef __attribute__((ext_vector_type(8))) short short8;   // 8 bf16 = 4 VGPRs
typedef __attribute__((ext_vector_type(4))) float f32x4;

// fp32 -> bf16 round-to-nearest-even (values are finite; no NaN care needed)
__device__ __forceinline__ ushort f2bf(float f){
    const unsigned u = __float_as_uint(f);
    return (ushort)((u + 0x7fffu + ((u >> 16) & 1u)) >> 16);
}
__device__ __forceinline__ float bf2f(ushort s){
    return __uint_as_float(((unsigned)s) << 16);
}
__device__ __forceinline__ float fast_tanh(float v){
    v = fminf(fmaxf(v, -15.0f), 15.0f);
    const float a = __expf(2.0f * v);
    return (a - 1.0f) / (a + 1.0f);
}

// ---------------------------------------------------------------------------
// Prep (transpose-only): W1 [e][k=256][h=128] fp32 -> W1t [e][h][k] bf16;
// Wp likewise. 96 blocks of 64x64 tiles. Unchanged from round 6 (verified).
__global__ __launch_bounds__(256) void prep_kernel(
    const float* __restrict__ W1, const float* __restrict__ Wp,
    ushort* __restrict__ W1t, ushort* __restrict__ Wpt)
{
    __shared__ float tile[64 * 68];   // 64x64 fp32 tile, pad 68 vs bank conflicts
    int b = blockIdx.x;
    const int t = threadIdx.x;
    const float* src; ushort* dst; int K;
    int k0, h0;
    if (b < 64){                                    // W1: 8e x 4kt x 2ht
        const int e = b >> 3, kt = (b >> 1) & 3, ht = b & 1;
        src = W1 + (size_t)e * DD * HH;  dst = W1t + (size_t)e * HH * DD;
        K = DD; k0 = kt * 64; h0 = ht * 64;
    } else {                                        // Wp: 8e x 2kt x 2ht
        b -= 64;
        const int e = b >> 2, kt = (b >> 1) & 1, ht = b & 1;
        src = Wp + (size_t)e * HH * HH;  dst = Wpt + (size_t)e * HH * HH;
        K = HH; k0 = kt * 64; h0 = ht * 64;
    }
    #pragma unroll
    for (int j = 0; j < 4; j++){
        const int idx = t + 256 * j;               // 1024 float4 = 64x64
        const int kk = idx >> 4, hh = (idx & 15) * 4;
        const float4 v = *(const float4*)(src + (size_t)(k0 + kk) * HH + h0 + hh);
        *(float4*)&tile[kk * 68 + hh] = v;
    }
    __syncthreads();
    #pragma unroll
    for (int j = 0; j < 4; j++){
        const int idx = t + 256 * j;
        const int hh = idx >> 4, kk = (idx & 15) * 4;
        ushort4 o;
        o.x = f2bf(tile[(kk + 0) * 68 + hh]);
        o.y = f2bf(tile[(kk + 1) * 68 + hh]);
        o.z = f2bf(tile[(kk + 2) * 68 + hh]);
        o.w = f2bf(tile[(kk + 3) * 68 + hh]);
        *(ushort4*)&dst[(size_t)(h0 + hh) * K + k0 + kk] = o;
    }
}

// ---------------------------------------------------------------------------
// Dense kernel v3: 256 blocks x 512 threads, 64 rows/block, ~63 KB LDS ->
// 2 blocks/CU; __launch_bounds__(512,1) so the allocator is NOT capped
// (rounds 3/6 proved the 2nd-arg cap produces VGPR=40 + scratch spill).
//
// Wave layout: wave w owns output cols [w*16, w*16+16) for ALL 64 rows
// (4 row-tiles, acc[4]). No wave duplicates any B-fragment -> block-level
// weight traffic = W1t+Wpt exactly once (768 KB, L2-resident).
//
// Self-contained: stages X (fp32->bf16), routes its own 64 rows with
// BIT-IDENTICAL gating math (fp32 dots, same shfl tree, same top-2 +
// 2-way softmax), then computes all 8 experts densely; per-row top-2
// weights select contributions (w=0 exactly for non-picked experts).
//
// Bias fix vs rounds 4-6: bo[e] is added by exactly ONE lane per row
// (wid==0 && m16==0) BEFORE the m16-reduce; previous dense versions added
// it on all 16 m16-lanes (16x over-count, masked by bo==0 in this test).
__global__ __launch_bounds__(512, 1) void dense_kernel(
    const float* __restrict__ x, const float* __restrict__ Wg,
    const ushort* __restrict__ W1t, const float* __restrict__ b1,
    const ushort* __restrict__ Wpt, const float* __restrict__ bp,
    const float* __restrict__ mix_logit, const float* __restrict__ Wo,
    const float* __restrict__ bo, float* __restrict__ out)
{
    __shared__ __align__(16) float WgT[EE][DD];   // 8 KB
    __shared__ ushort Xs[RPB * XS_S];             // 33.8 KB
    __shared__ ushort coreS[RPB * CS_S];          // 17.4 KB
    __shared__ int    le[2 * RPB];                // e0 at [s], e1 at [RPB+s]
    __shared__ float  lw[2 * RPB];
    __shared__ float  wES[RPB];
    __shared__ float  redS[8][RPB];               // 2 KB
    __shared__ float  mvS[EE], boS[EE];

    const int t = threadIdx.x;
    const int rowBase = blockIdx.x * RPB;
    const int lane = t & 63;
    const int wid  = t >> 6;

    // ---- stage WgT (first 256 threads, verified pattern) + consts ----
    if (t < 256){
        const float4* g = (const float4*)(Wg + t * EE);
        const float4 a = g[0], b = g[1];
        WgT[0][t] = a.x; WgT[1][t] = a.y; WgT[2][t] = a.z; WgT[3][t] = a.w;
        WgT[4][t] = b.x; WgT[5][t] = b.y; WgT[6][t] = b.z; WgT[7][t] = b.w;
    }
    if (t < EE){ mvS[t] = 1.0f / (1.0f + __expf(-mix_logit[t])); boS[t] = bo[t]; }

    // ---- stage Xs: 64 rows x 32 chunks (8 bf16), 2048 chunks, 4/thread ----
    #pragma unroll
    for (int i = 0; i < 4; i++){
        const int c   = i * 512 + t;               // lane-consecutive chunks
        const int row = c >> 5, cc = c & 31;
        const float* xp = x + (size_t)(rowBase + row) * DD + cc * 8;
        const float4 v0 = *(const float4*)xp;
        const float4 v1 = *(const float4*)(xp + 4);
        short8 o;
        o[0] = (short)f2bf(v0.x); o[1] = (short)f2bf(v0.y);
        o[2] = (short)f2bf(v0.z); o[3] = (short)f2bf(v0.w);
        o[4] = (short)f2bf(v1.x); o[5] = (short)f2bf(v1.y);
        o[6] = (short)f2bf(v1.z); o[7] = (short)f2bf(v1.w);
        *(short8*)&Xs[row * XS_S + cc * 8] = o;
    }
    __syncthreads();

    // ---- routing: 8 waves x 8 rows, per-row math bit-identical to verified ----
    for (int it = 0; it < 8; it++){
        const int slot = wid * 8 + it;
        const int row  = rowBase + slot;
        const float4 xv = *(const float4*)(x + (size_t)row * DD + lane * 4);
        float p[EE];
        #pragma unroll
        for (int e = 0; e < EE; e++){
            const float4 ww = *(const float4*)&WgT[e][lane * 4];
            p[e] = xv.x * ww.x + xv.y * ww.y + xv.z * ww.z + xv.w * ww.w;
        }
        #pragma unroll
        for (int off = 32; off >= 1; off >>= 1){
            #pragma unroll
            for (int e = 0; e < EE; e++) p[e] += __shfl_down(p[e], off, 64);
        }
        if (lane == 0){
            int e0 = 0; float l0 = p[0];
            #pragma unroll
            for (int e = 1; e < EE; e++){ if (p[e] > l0){ l0 = p[e]; e0 = e; } }
            int e1 = -1; float l1 = -3.0e38f;
            #pragma unroll
            for (int e = 0; e < EE; e++){ if (e != e0 && p[e] > l1){ l1 = p[e]; e1 = e; } }
            const float tt  = __expf(l1 - l0);            // <= 1
            const float inv = 1.0f / (1.0f + tt);
            le[slot]       = e0;  lw[slot]       = inv;
            le[RPB + slot] = e1;  lw[RPB + slot] = tt * inv;
        }
    }
    __syncthreads();

    // ---- dense expert loop: wave w owns cols c0 = w*16, all 64 rows ----
    const int m16 = lane & 15;
    const int q   = lane >> 4;
    const int c0  = wid * 16;

    float red[4][4];
    #pragma unroll
    for (int rt = 0; rt < 4; rt++)
        #pragma unroll
        for (int j = 0; j < 4; j++) red[rt][j] = 0.0f;

    #pragma unroll 1
    for (int e = 0; e < EE; e++){
        // per-row weight for this expert (0 if not in the row's top-2);
        // end-of-iteration barrier orders this vs prior epilogue reads
        if (t < RPB)
            wES[t] = (le[t] == e) ? lw[t] : ((le[RPB + t] == e) ? lw[RPB + t] : 0.0f);

        // ---- GEMM1: core_pre = X @ W1[e] + b1[e]  (64 rows x 16 cols/wave) ----
        f32x4 acc[4];
        {
            const float bj = b1[e * HH + c0 + m16];
            #pragma unroll
            for (int rt = 0; rt < 4; rt++) acc[rt] = (f32x4){bj, bj, bj, bj};
        }
        const ushort* W1te = W1t + (size_t)e * HH * DD;
        #pragma unroll
        for (int ks = 0; ks < 8; ks++){
            const short8 bfr = *(const short8*)&W1te[(size_t)(c0 + m16) * DD + ks * 32 + q * 8];
            #pragma unroll
            for (int rt = 0; rt < 4; rt++){
                const short8 af = *(const short8*)&Xs[(rt * 16 + m16) * XS_S + ks * 32 + q * 8];
                acc[rt] = __builtin_amdgcn_mfma_f32_16x16x32_bf16(af, bfr, acc[rt], 0, 0, 0);
            }
        }
        // relu -> bf16 core into shared coreS (C layout: col=m16, row=q*4+j)
        #pragma unroll
        for (int rt = 0; rt < 4; rt++)
            #pragma unroll
            for (int j = 0; j < 4; j++)
                coreS[(rt * 16 + q * 4 + j) * CS_S + c0 + m16] =
                    f2bf(fmaxf(acc[rt][j], 0.0f));
        __syncthreads();   // coreS + wES visible to all waves

        // ---- GEMM2: plast_pre = core @ Wp[e] + bp[e] ----
        f32x4 acc2[4];
        {
            const float bj = bp[e * HH + c0 + m16];
            #pragma unroll
            for (int rt = 0; rt < 4; rt++) acc2[rt] = (f32x4){bj, bj, bj, bj};
        }
        const ushort* Wpte = Wpt + (size_t)e * HH * HH;
        #pragma unroll
        for (int ks = 0; ks < 4; ks++){
            const short8 bfr = *(const short8*)&Wpte[(size_t)(c0 + m16) * HH + ks * 32 + q * 8];
            #pragma unroll
            for (int rt = 0; rt < 4; rt++){
                const short8 af2 = *(const short8*)&coreS[(rt * 16 + m16) * CS_S + ks * 32 + q * 8];
                acc2[rt] = __builtin_amdgcn_mfma_f32_16x16x32_bf16(af2, bfr, acc2[rt], 0, 0, 0);
            }
        }

        // ---- epilogue partial: red += w_row * (col contribution [+ bo once]) ----
        const float mv   = mvS[e];
        const float om   = 1.0f - mv;
        const float wo   = Wo[e * HH + c0 + m16];
        const float badd = (wid == 0 && m16 == 0) ? boS[e] : 0.0f;  // once per row

        #pragma unroll
        for (int rt = 0; rt < 4; rt++)
            #pragma unroll
            for (int j = 0; j < 4; j++){
                const int row = rt * 16 + q * 4 + j;   // block-local row
                const float pl = fast_tanh(acc2[rt][j]);
                const float cv = bf2f(coreS[row * CS_S + c0 + m16]);
                const float s  = (om * cv + mv * pl) * wo;
                red[rt][j] = fmaf(wES[row], s + badd, red[rt][j]);
            }
        __syncthreads();   // coreS/wES consumed; next e may overwrite
    }

    // ---- final: reduce over m16 (16 cols), cross-wave sum via redS, store ----
    #pragma unroll
    for (int off = 8; off >= 1; off >>= 1)
        #pragma unroll
        for (int rt = 0; rt < 4; rt++)
            #pragma unroll
            for (int j = 0; j < 4; j++)
                red[rt][j] += __shfl_xor(red[rt][j], off, 64);

    if (m16 == 0)
        #pragma unroll
        for (int rt = 0; rt < 4; rt++)
            #pragma unroll
            for (int j = 0; j < 4; j++)
                redS[wid][rt * 16 + q * 4 + j] = red[rt][j];
    __syncthreads();

    if (t < RPB){
        float s = 0.0f;
        #pragma unroll
        for (int w = 0; w < 8; w++) s += redS[w][t];
        out[rowBase + t] = s;
    }
}

// ---------------------------------------------------------------------------
extern "C" void kernel_launch(void* const* d_in, const int* in_sizes, int n_in,
                              void* d_out, int out_size, void* d_ws, size_t ws_size,
                              hipStream_t stream) {
    (void)in_sizes; (void)n_in; (void)out_size; (void)ws_size;
    const float* x   = (const float*)d_in[0];
    const float* Wg  = (const float*)d_in[1];
    const float* W1  = (const float*)d_in[2];
    const float* b1  = (const float*)d_in[3];
    const float* Wp  = (const float*)d_in[4];
    const float* bp  = (const float*)d_in[5];
    const float* ml  = (const float*)d_in[6];
    const float* Wo  = (const float*)d_in[7];
    const float* bo  = (const float*)d_in[8];
    float* out = (float*)d_out;

    // ws layout: W1t E*H*D*2 = 512 KB | Wpt E*H*H*2 = 256 KB. Nothing else.
    char*   ws  = (char*)d_ws;
    ushort* W1t = (ushort*)ws;
    ushort* Wpt = W1t + (size_t)EE * HH * DD;

    // 2 dispatches, no memsets, no atomics, no gather.
    prep_kernel<<<TBLK, 256, 0, stream>>>(W1, Wp, W1t, Wpt);
    dense_kernel<<<BB / RPB, 512, 0, stream>>>(
        x, Wg, W1t, b1, Wpt, bp, ml, Wo, bo, out);
}